// Round 8
// baseline (53.292 us; speedup 1.0000x reference)
//
#include <hip/hip_runtime.h>
#include <math.h>

#define NUM_GRAPHS 512
#define D 128
#define MAGIC 0x5A17C0DE

__device__ inline int lower_bound_i(const int* __restrict__ b, int n, int v) {
    int lo = 0, hi = n;
    while (lo < hi) {
        int mid = (lo + hi) >> 1;
        if (b[mid] < v) lo = mid + 1; else hi = mid;
    }
    return lo;
}

__device__ inline void add4(float4& a, const float4 v) {
    a.x += v.x; a.y += v.y; a.z += v.z; a.w += v.w;
}

// ws layout: flags int[2048] | gpart float[2048*128] | dsq float[1024]
// Block j: s = j/6, k = j%6. k<4: producer A(s, w=k>>1, h=k&1) — sums half a
// segment, agent-stores partial[128] then MAGIC flag (idempotent: partials are
// input-determined, so stale flags from a previous call are harmless — the
// consumer reads bit-identical values). k>=4: consumer C(s, w=k-4) — spins on
// the 4 flags, combines halves in fixed order (deterministic), normalizes via
// epilogue scalars, computes per-row JSD dots over its own modality's rows.
// Producers outnumber residency -> generations pipeline -> HBM streaming (A)
// overlaps L3 re-read + VALU (C). No fences, no atomics RMW, no L2 writebacks.
__global__ __launch_bounds__(256, 4) void gcl_main(
    const float* __restrict__ z1, const float* __restrict__ z2,
    const int* __restrict__ b1, const int* __restrict__ b2,
    int* __restrict__ flags, float* __restrict__ gpart,
    float* __restrict__ dsq, int N)
{
    const int j = blockIdx.x;
    const int s = j / 6;
    const int k = j % 6;
    const int t = threadIdx.x;

    __shared__ int bnds[2];

    if (k < 4) {
        // ---------------- producer: half-segment partial sum ----------------
        const int w = k >> 1, h = k & 1;
        const float* z = w ? z2 : z1;
        const int*   b = w ? b2 : b1;
        if (t < 2) bnds[t] = lower_bound_i(b, N, s + t);
        __syncthreads();
        int start = bnds[0], end = bnds[1];
        const int mid = start + ((end - start) >> 1);
        if (h == 0) end = mid; else start = mid;

        const int r = t >> 5;   // 0..7
        const int c = t & 31;   // float4 col
        const float4* Z = reinterpret_cast<const float4*>(z);
        float4 a0 = make_float4(0.f, 0.f, 0.f, 0.f), a1 = a0, a2 = a0, a3 = a0;
        int row = start + r;
        for (; row + 24 < end; row += 32) {
            float4 v0 = Z[(size_t)row * 32 + c];
            float4 v1 = Z[(size_t)(row + 8)  * 32 + c];
            float4 v2 = Z[(size_t)(row + 16) * 32 + c];
            float4 v3 = Z[(size_t)(row + 24) * 32 + c];
            add4(a0, v0); add4(a1, v1); add4(a2, v2); add4(a3, v3);
        }
        for (; row < end; row += 8) add4(a0, Z[(size_t)row * 32 + c]);
        add4(a0, a1); add4(a2, a3); add4(a0, a2);

        __shared__ float4 part[8][32];
        part[r][c] = a0;
        __syncthreads();
        if (t < 32) {
            float4 sum = part[0][t];
#pragma unroll
            for (int g = 1; g < 8; ++g) add4(sum, part[g][t]);
            float* dst = gpart + (size_t)(s * 4 + w * 2 + h) * D + 4 * t;
            __hip_atomic_store(&dst[0], sum.x, __ATOMIC_RELAXED, __HIP_MEMORY_SCOPE_AGENT);
            __hip_atomic_store(&dst[1], sum.y, __ATOMIC_RELAXED, __HIP_MEMORY_SCOPE_AGENT);
            __hip_atomic_store(&dst[2], sum.z, __ATOMIC_RELAXED, __HIP_MEMORY_SCOPE_AGENT);
            __hip_atomic_store(&dst[3], sum.w, __ATOMIC_RELAXED, __HIP_MEMORY_SCOPE_AGENT);
            asm volatile("s_waitcnt vmcnt(0)" ::: "memory");   // per-wave: all 32 lanes' stores drained
            if (t == 0)
                __hip_atomic_store(&flags[s * 4 + w * 2 + h], MAGIC,
                                   __ATOMIC_RELAXED, __HIP_MEMORY_SCOPE_AGENT);
        }
    } else {
        // ---------------- consumer: dots + JSD for modality w ----------------
        const int w = k - 4;
        const float* z = w ? z2 : z1;
        const int*   b = w ? b2 : b1;
        __shared__ float gown[D], gcrs[D];
        __shared__ float invs[2];
        __shared__ float warr[4];

        if (t < 2) bnds[t] = lower_bound_i(b, N, s + t);
        if (t < 4) {            // lanes 0..3 spin one flag each (s*4 + {0,1,2,3})
            const int fi = s * 4 + t;
            int guard = 0;
            while (__hip_atomic_load(&flags[fi], __ATOMIC_RELAXED,
                                     __HIP_MEMORY_SCOPE_AGENT) != MAGIC) {
                __builtin_amdgcn_s_sleep(2);
                if (++guard > (1 << 22)) break;   // safety: fail visibly, never hang
            }
        }
        __syncthreads();
        const int start = bnds[0], end = bnds[1];

        // combine halves (fixed order -> deterministic); own = w, cross = w^1
        if (t < 128) {
            const float* p0 = gpart + (size_t)(s * 4 + w * 2 + 0) * D;
            const float* p1 = gpart + (size_t)(s * 4 + w * 2 + 1) * D;
            gown[t] = __hip_atomic_load(&p0[t], __ATOMIC_RELAXED, __HIP_MEMORY_SCOPE_AGENT)
                    + __hip_atomic_load(&p1[t], __ATOMIC_RELAXED, __HIP_MEMORY_SCOPE_AGENT);
        } else {
            const int tc = t - 128, wo = w ^ 1;
            const float* p0 = gpart + (size_t)(s * 4 + wo * 2 + 0) * D;
            const float* p1 = gpart + (size_t)(s * 4 + wo * 2 + 1) * D;
            gcrs[tc] = __hip_atomic_load(&p0[tc], __ATOMIC_RELAXED, __HIP_MEMORY_SCOPE_AGENT)
                     + __hip_atomic_load(&p1[tc], __ATOMIC_RELAXED, __HIP_MEMORY_SCOPE_AGENT);
        }
        __syncthreads();

        // inverse norms (raw g kept; scale folded into epilogue)
        const int wid = t >> 6, lane = t & 63;
        if (wid == 0) {
            float x = gown[lane], y = gown[lane + 64];
            float ssn = x * x + y * y;
#pragma unroll
            for (int m = 1; m <= 32; m <<= 1) ssn += __shfl_xor(ssn, m, 64);
            if (lane == 0) invs[0] = 1.0f / fmaxf(sqrtf(ssn), 1e-12f);
        } else if (wid == 1) {
            float x = gcrs[lane], y = gcrs[lane + 64];
            float ssn = x * x + y * y;
#pragma unroll
            for (int m = 1; m <= 32; m <<= 1) ssn += __shfl_xor(ssn, m, 64);
            if (lane == 0) invs[1] = 1.0f / fmaxf(sqrtf(ssn), 1e-12f);
        }
        __syncthreads();
        const float invP = invs[0], invC = invs[1];

        // quad-per-row dots (g raw in regs, scaled at epilogue)
        const int q   = t & 3;
        const int rid = t >> 2;
        float4 gpv[8], gcv[8];
        {
            const float4* GP = reinterpret_cast<const float4*>(gown) + q * 8;
            const float4* GC = reinterpret_cast<const float4*>(gcrs) + q * 8;
#pragma unroll
            for (int i = 0; i < 8; ++i) { gpv[i] = GP[i]; gcv[i] = GC[i]; }
        }
        const float4* Z = reinterpret_cast<const float4*>(z);
        float acc = 0.f;
        for (int row = start + rid; row < end; row += 64) {
            float p = 0.f, cr = 0.f, ss = 0.f;
#pragma unroll
            for (int i = 0; i < 8; ++i) {
                float4 zv = Z[(size_t)row * 32 + q * 8 + i];
                p  += zv.x * gpv[i].x + zv.y * gpv[i].y + zv.z * gpv[i].z + zv.w * gpv[i].w;
                cr += zv.x * gcv[i].x + zv.y * gcv[i].y + zv.z * gcv[i].z + zv.w * gcv[i].w;
                ss += zv.x * zv.x + zv.y * zv.y + zv.z * zv.z + zv.w * zv.w;
            }
            p  += __shfl_xor(p, 1, 64);  p  += __shfl_xor(p, 2, 64);
            cr += __shfl_xor(cr, 1, 64); cr += __shfl_xor(cr, 2, 64);
            ss += __shfl_xor(ss, 1, 64); ss += __shfl_xor(ss, 2, 64);
            if (q == 0) {
                const float invz  = 1.0f / fmaxf(sqrtf(ss), 1e-12f);
                const float pos   = p  * invP * invz;
                const float cross = cr * invC * invz;
                const float d = log1pf(__expf(-cross)) - log1pf(__expf(-pos));
                acc += d * d;
            }
        }
#pragma unroll
        for (int m = 1; m <= 32; m <<= 1) acc += __shfl_xor(acc, m, 64);
        if ((t & 63) == 0) warr[t >> 6] = acc;
        __syncthreads();
        if (t == 0)
            dsq[w * NUM_GRAPHS + s] = warr[0] + warr[1] + warr[2] + warr[3];
    }
}

// Single block, 1024 threads: dsq[0..511] -> s0, dsq[512..1023] -> s1.
__global__ __launch_bounds__(1024) void finalize_kernel(const float* __restrict__ dsq,
                                                        float* __restrict__ out) {
    const int t = threadIdx.x;
    float v = dsq[t];
#pragma unroll
    for (int m = 1; m <= 32; m <<= 1) v += __shfl_xor(v, m, 64);
    __shared__ float w[16];
    if ((t & 63) == 0) w[t >> 6] = v;
    __syncthreads();
    if (t == 0) {
        float s0 = 0.f, s1 = 0.f;
#pragma unroll
        for (int i = 0; i < 8; ++i)  s0 += w[i];
#pragma unroll
        for (int i = 8; i < 16; ++i) s1 += w[i];
        out[0] = sqrtf(s0) + sqrtf(s1);
    }
}

extern "C" void kernel_launch(void* const* d_in, const int* in_sizes, int n_in,
                              void* d_out, int out_size, void* d_ws, size_t ws_size,
                              hipStream_t stream) {
    const float* z1 = (const float*)d_in[0];
    const float* z2 = (const float*)d_in[1];
    const int*   b1 = (const int*)d_in[2];
    const int*   b2 = (const int*)d_in[3];
    const int N = in_sizes[2];

    int*   flags = (int*)d_ws;                         // 2048 ints
    float* gpart = (float*)(flags + 2048);             // 2048*128 floats
    float* dsq   = gpart + (size_t)2048 * D;           // 1024 floats

    gcl_main<<<6 * NUM_GRAPHS, 256, 0, stream>>>(z1, z2, b1, b2,
                                                 flags, gpart, dsq, N);
    finalize_kernel<<<1, 1024, 0, stream>>>(dsq, (float*)d_out);
}

// Round 9
// 43.756 us; speedup vs baseline: 1.2179x; 1.2179x over previous
//
#include <hip/hip_runtime.h>
#include <math.h>

#define NUM_GRAPHS 512
#define D 128
#define CAP 272      // staged rows per (segment,modality): mean 195 + 5.5 sigma; overflow -> global fallback
#define ROWB 256     // bytes per staged bf16 row (128 * 2B)

__device__ inline int lower_bound_i(const int* __restrict__ b, int n, int v) {
    int lo = 0, hi = n;
    while (lo < hi) {
        int mid = (lo + hi) >> 1;
        if (b[mid] < v) lo = mid + 1; else hi = mid;
    }
    return lo;
}

__device__ inline void add4(float4& a, const float4 v) {
    a.x += v.x; a.y += v.y; a.z += v.z; a.w += v.w;
}

__device__ inline unsigned int bf16rn(float x) {   // round-to-nearest-even bf16 (as u16)
    unsigned int b = __float_as_uint(x);
    b += 0x7fffu + ((b >> 16) & 1u);
    return b >> 16;
}

// Stage one float4 (fp32 dims 4c..4c+3 of row idx) as 8B of bf16 into LDS.
// Chunk-XOR swizzle (16B chunks, ^ (idx&7)) -> ds_read_b128 in phase C is ~2-way (free).
__device__ inline void stage(unsigned char* zb, int idx, int c, float4 v) {
    if (idx >= CAP) return;
    const unsigned int lo = bf16rn(v.x) | (bf16rn(v.y) << 16);
    const unsigned int hi = bf16rn(v.z) | (bf16rn(v.w) << 16);
    const int chunk = (c >> 1) ^ (idx & 7);
    *reinterpret_cast<uint2*>(zb + (size_t)idx * ROWB + chunk * 16 + (c & 1) * 8)
        = make_uint2(lo, hi);
}

// One block per segment s, 512 threads; half (t>>8) = modality. Phase A streams
// the segment's rows ONCE from HBM: fp32 segment-sum (exact) + bf16 LDS copy.
// Phase B normalizes g into LDS. Phase C computes dots/JSD reading z from LDS
// (no second global pass - R7 showed the L3 re-read ran at only ~4 TB/s).
__global__ __launch_bounds__(512, 1) void fused_gcl(
    const float* __restrict__ z1, const float* __restrict__ z2,
    const int* __restrict__ b1, const int* __restrict__ b2,
    float* __restrict__ dsq, int N)
{
    extern __shared__ unsigned char smem[];    // 2 * CAP * ROWB bytes
    const int s    = blockIdx.x;
    const int t    = threadIdx.x;
    const int half = t >> 8;     // 0: z1/b1, 1: z2/b2
    const int tt   = t & 255;

    const float* z = half ? z2 : z1;
    const int*   b = half ? b2 : b1;
    unsigned char* zb = smem + (size_t)half * CAP * ROWB;

    __shared__ int    bnds[2][2];
    __shared__ float4 part[2][8][32];
    __shared__ float  gbuf[2][D];
    __shared__ float  warr[2][4];

    if (tt < 2) bnds[half][tt] = lower_bound_i(b, N, s + tt);
    __syncthreads();
    const int start = bnds[half][0], end = bnds[half][1];
    const int cnt    = end - start;
    const int staged = cnt < CAP ? cnt : CAP;

    // ---- Phase A: single HBM pass: fp32 sum + bf16 stage ----
    {
        const int r = tt >> 5;   // 0..7
        const int c = tt & 31;   // float4 col
        const float4* Z = reinterpret_cast<const float4*>(z);
        float4 a0 = make_float4(0.f, 0.f, 0.f, 0.f), a1 = a0, a2 = a0, a3 = a0;
        int row = start + r;
        for (; row + 24 < end; row += 32) {
            float4 v0 = Z[(size_t)row * 32 + c];
            float4 v1 = Z[(size_t)(row + 8)  * 32 + c];
            float4 v2 = Z[(size_t)(row + 16) * 32 + c];
            float4 v3 = Z[(size_t)(row + 24) * 32 + c];
            add4(a0, v0); add4(a1, v1); add4(a2, v2); add4(a3, v3);
            stage(zb, row - start,      c, v0);
            stage(zb, row - start + 8,  c, v1);
            stage(zb, row - start + 16, c, v2);
            stage(zb, row - start + 24, c, v3);
        }
        for (; row < end; row += 8) {
            float4 v = Z[(size_t)row * 32 + c];
            add4(a0, v);
            stage(zb, row - start, c, v);
        }
        add4(a0, a1); add4(a2, a3); add4(a0, a2);
        part[half][r][c] = a0;
    }
    __syncthreads();

    // ---- Phase B: reduce + normalize g into gbuf[half] ----
    if (tt < 32) {
        float4 sum = part[half][0][tt];
#pragma unroll
        for (int g = 1; g < 8; ++g) add4(sum, part[half][g][tt]);
        float ss = sum.x * sum.x + sum.y * sum.y + sum.z * sum.z + sum.w * sum.w;
#pragma unroll
        for (int m = 1; m <= 16; m <<= 1) ss += __shfl_xor(ss, m, 64);
        const float inv = 1.0f / fmaxf(sqrtf(ss), 1e-12f);
        sum.x *= inv; sum.y *= inv; sum.z *= inv; sum.w *= inv;
        reinterpret_cast<float4*>(gbuf[half])[tt] = sum;
    }
    __syncthreads();

    // ---- Phase C: quad-per-row dots + JSD, z from LDS (bf16) ----
    const int q   = tt & 3;    // quarter of row: dims 32q..32q+31
    const int rid = tt >> 2;   // 0..63
    float4 gpv[8], gcv[8];
    {
        const float4* GP = reinterpret_cast<const float4*>(gbuf[half])     + q * 8;
        const float4* GC = reinterpret_cast<const float4*>(gbuf[half ^ 1]) + q * 8;
#pragma unroll
        for (int i = 0; i < 8; ++i) { gpv[i] = GP[i]; gcv[i] = GC[i]; }
    }

    float acc = 0.f;
    for (int idx = rid; idx < staged; idx += 64) {
        const unsigned char* rowp = zb + (size_t)idx * ROWB;
        const int x = idx & 7;
        float p = 0.f, cr = 0.f, ssv = 0.f;
#pragma unroll
        for (int j = 0; j < 4; ++j) {
            const int chunk = (q * 4 + j) ^ x;
            const uint4 u = *reinterpret_cast<const uint4*>(rowp + chunk * 16);
            const float4 gp = gpv[2 * j], gq = gpv[2 * j + 1];
            const float4 hp = gcv[2 * j], hq = gcv[2 * j + 1];
            const float f0 = __uint_as_float(u.x << 16);
            const float f1 = __uint_as_float(u.x & 0xffff0000u);
            const float f2 = __uint_as_float(u.y << 16);
            const float f3 = __uint_as_float(u.y & 0xffff0000u);
            const float f4 = __uint_as_float(u.z << 16);
            const float f5 = __uint_as_float(u.z & 0xffff0000u);
            const float f6 = __uint_as_float(u.w << 16);
            const float f7 = __uint_as_float(u.w & 0xffff0000u);
            p   += f0*gp.x + f1*gp.y + f2*gp.z + f3*gp.w
                 + f4*gq.x + f5*gq.y + f6*gq.z + f7*gq.w;
            cr  += f0*hp.x + f1*hp.y + f2*hp.z + f3*hp.w
                 + f4*hq.x + f5*hq.y + f6*hq.z + f7*hq.w;
            ssv += f0*f0 + f1*f1 + f2*f2 + f3*f3 + f4*f4 + f5*f5 + f6*f6 + f7*f7;
        }
        p   += __shfl_xor(p, 1, 64);   p   += __shfl_xor(p, 2, 64);
        cr  += __shfl_xor(cr, 1, 64);  cr  += __shfl_xor(cr, 2, 64);
        ssv += __shfl_xor(ssv, 1, 64); ssv += __shfl_xor(ssv, 2, 64);
        if (q == 0) {
            const float invz  = 1.0f / fmaxf(sqrtf(ssv), 1e-12f);
            const float pos   = p  * invz;
            const float cross = cr * invz;
            const float d = log1pf(__expf(-cross)) - log1pf(__expf(-pos));
            acc += d * d;
        }
    }
    // overflow rows (cnt > CAP): exact fp32 from global (statistically never)
    for (int idx = staged + rid; idx < cnt; idx += 64) {
        const int row = start + idx;
        const float4* Z = reinterpret_cast<const float4*>(z);
        float p = 0.f, cr = 0.f, ssv = 0.f;
#pragma unroll
        for (int i = 0; i < 8; ++i) {
            float4 zv = Z[(size_t)row * 32 + q * 8 + i];
            p   += zv.x * gpv[i].x + zv.y * gpv[i].y + zv.z * gpv[i].z + zv.w * gpv[i].w;
            cr  += zv.x * gcv[i].x + zv.y * gcv[i].y + zv.z * gcv[i].z + zv.w * gcv[i].w;
            ssv += zv.x * zv.x + zv.y * zv.y + zv.z * zv.z + zv.w * zv.w;
        }
        p   += __shfl_xor(p, 1, 64);   p   += __shfl_xor(p, 2, 64);
        cr  += __shfl_xor(cr, 1, 64);  cr  += __shfl_xor(cr, 2, 64);
        ssv += __shfl_xor(ssv, 1, 64); ssv += __shfl_xor(ssv, 2, 64);
        if (q == 0) {
            const float invz  = 1.0f / fmaxf(sqrtf(ssv), 1e-12f);
            const float pos   = p  * invz;
            const float cross = cr * invz;
            const float d = log1pf(__expf(-cross)) - log1pf(__expf(-pos));
            acc += d * d;
        }
    }

#pragma unroll
    for (int m = 1; m <= 32; m <<= 1) acc += __shfl_xor(acc, m, 64);
    if ((tt & 63) == 0) warr[half][tt >> 6] = acc;
    __syncthreads();
    if (tt == 0)
        dsq[half * NUM_GRAPHS + s] = warr[half][0] + warr[half][1]
                                   + warr[half][2] + warr[half][3];
}

// Single block, 1024 threads: dsq[0..511] -> s0, dsq[512..1023] -> s1.
__global__ __launch_bounds__(1024) void finalize_kernel(const float* __restrict__ dsq,
                                                        float* __restrict__ out) {
    const int t = threadIdx.x;
    float v = dsq[t];
#pragma unroll
    for (int m = 1; m <= 32; m <<= 1) v += __shfl_xor(v, m, 64);
    __shared__ float w[16];
    if ((t & 63) == 0) w[t >> 6] = v;
    __syncthreads();
    if (t == 0) {
        float s0 = 0.f, s1 = 0.f;
#pragma unroll
        for (int i = 0; i < 8; ++i)  s0 += w[i];
#pragma unroll
        for (int i = 8; i < 16; ++i) s1 += w[i];
        out[0] = sqrtf(s0) + sqrtf(s1);
    }
}

extern "C" void kernel_launch(void* const* d_in, const int* in_sizes, int n_in,
                              void* d_out, int out_size, void* d_ws, size_t ws_size,
                              hipStream_t stream) {
    const float* z1 = (const float*)d_in[0];
    const float* z2 = (const float*)d_in[1];
    const int*   b1 = (const int*)d_in[2];
    const int*   b2 = (const int*)d_in[3];
    const int N = in_sizes[2];

    float* dsq = (float*)d_ws;   // 1024 floats, fully written every call

    const int smem_bytes = 2 * CAP * ROWB;   // 139264 B dynamic (+ ~9.3 KB static)
    (void)hipFuncSetAttribute((const void*)fused_gcl,
                              hipFuncAttributeMaxDynamicSharedMemorySize, smem_bytes);

    fused_gcl<<<NUM_GRAPHS, 512, smem_bytes, stream>>>(z1, z2, b1, b2, dsq, N);
    finalize_kernel<<<1, 1024, 0, stream>>>(dsq, (float*)d_out);
}

// Round 10
// 37.599 us; speedup vs baseline: 1.4174x; 1.1637x over previous
//
#include <hip/hip_runtime.h>
#include <math.h>

#define NUM_GRAPHS 512
#define D 128
#define CAP 136      // staged rows per (segment,modality); sized so 2 blocks/CU fit in LDS
#define ROWB 256     // bytes per staged bf16 row (128 * 2B)

__device__ inline int lower_bound_i(const int* __restrict__ b, int n, int v) {
    int lo = 0, hi = n;
    while (lo < hi) {
        int mid = (lo + hi) >> 1;
        if (b[mid] < v) lo = mid + 1; else hi = mid;
    }
    return lo;
}

__device__ inline void add4(float4& a, const float4 v) {
    a.x += v.x; a.y += v.y; a.z += v.z; a.w += v.w;
}

__device__ inline unsigned int bf16rn(float x) {   // round-to-nearest-even bf16 (as u16)
    unsigned int b = __float_as_uint(x);
    b += 0x7fffu + ((b >> 16) & 1u);
    return b >> 16;
}

// Stage one float4 (fp32 dims 4c..4c+3 of row idx) as 8B of bf16 into LDS.
// Chunk-XOR swizzle (16B chunks, ^ (idx&7)) keeps phase-C ds_read conflicts low.
__device__ inline void stage(unsigned char* zb, int idx, int c, float4 v) {
    if (idx >= CAP) return;
    const unsigned int lo = bf16rn(v.x) | (bf16rn(v.y) << 16);
    const unsigned int hi = bf16rn(v.z) | (bf16rn(v.w) << 16);
    const int chunk = (c >> 1) ^ (idx & 7);
    *reinterpret_cast<uint2*>(zb + (size_t)idx * ROWB + chunk * 16 + (c & 1) * 8)
        = make_uint2(lo, hi);
}

// One block per segment s, 512 threads; half (t>>8) = modality.
// Phase A: single HBM pass: fp32 segment-sum (exact) + bf16 LDS copy of the
//          first CAP rows. R9 lesson: LDS for ALL rows -> 1 block/CU -> 8
//          waves/CU -> latency-bound 1 TB/s. CAP=136 -> 79KB/block -> 2
//          blocks/CU (16 waves) for ~2x streaming BW; the ~30% un-staged rows
//          fall back to global in phase C and hit L3 (just streamed).
// Phase B: normalize g into LDS. Phase C: quad-per-row dots + JSD.
__global__ __launch_bounds__(512, 4) void fused_gcl(
    const float* __restrict__ z1, const float* __restrict__ z2,
    const int* __restrict__ b1, const int* __restrict__ b2,
    float* __restrict__ dsq, int N)
{
    extern __shared__ unsigned char smem[];    // 2 * CAP * ROWB bytes
    const int s    = blockIdx.x;
    const int t    = threadIdx.x;
    const int half = t >> 8;     // 0: z1/b1, 1: z2/b2
    const int tt   = t & 255;

    const float* z = half ? z2 : z1;
    const int*   b = half ? b2 : b1;
    unsigned char* zb = smem + (size_t)half * CAP * ROWB;

    __shared__ int    bnds[2][2];
    __shared__ float4 part[2][8][32];
    __shared__ float  gbuf[2][D];
    __shared__ float  warr[2][4];

    if (tt < 2) bnds[half][tt] = lower_bound_i(b, N, s + tt);
    __syncthreads();
    const int start = bnds[half][0], end = bnds[half][1];
    const int cnt    = end - start;
    const int staged = cnt < CAP ? cnt : CAP;

    // ---- Phase A: single HBM pass: fp32 sum + bf16 stage (first CAP rows) ----
    {
        const int r = tt >> 5;   // 0..7
        const int c = tt & 31;   // float4 col
        const float4* Z = reinterpret_cast<const float4*>(z);
        float4 a0 = make_float4(0.f, 0.f, 0.f, 0.f), a1 = a0, a2 = a0, a3 = a0;
        int row = start + r;
        for (; row + 24 < end; row += 32) {
            float4 v0 = Z[(size_t)row * 32 + c];
            float4 v1 = Z[(size_t)(row + 8)  * 32 + c];
            float4 v2 = Z[(size_t)(row + 16) * 32 + c];
            float4 v3 = Z[(size_t)(row + 24) * 32 + c];
            add4(a0, v0); add4(a1, v1); add4(a2, v2); add4(a3, v3);
            stage(zb, row - start,      c, v0);
            stage(zb, row - start + 8,  c, v1);
            stage(zb, row - start + 16, c, v2);
            stage(zb, row - start + 24, c, v3);
        }
        for (; row < end; row += 8) {
            float4 v = Z[(size_t)row * 32 + c];
            add4(a0, v);
            stage(zb, row - start, c, v);
        }
        add4(a0, a1); add4(a2, a3); add4(a0, a2);
        part[half][r][c] = a0;
    }
    __syncthreads();

    // ---- Phase B: reduce + normalize g into gbuf[half] ----
    if (tt < 32) {
        float4 sum = part[half][0][tt];
#pragma unroll
        for (int g = 1; g < 8; ++g) add4(sum, part[half][g][tt]);
        float ss = sum.x * sum.x + sum.y * sum.y + sum.z * sum.z + sum.w * sum.w;
#pragma unroll
        for (int m = 1; m <= 16; m <<= 1) ss += __shfl_xor(ss, m, 64);
        const float inv = 1.0f / fmaxf(sqrtf(ss), 1e-12f);
        sum.x *= inv; sum.y *= inv; sum.z *= inv; sum.w *= inv;
        reinterpret_cast<float4*>(gbuf[half])[tt] = sum;
    }
    __syncthreads();

    // ---- Phase C: quad-per-row dots + JSD ----
    const int q   = tt & 3;    // quarter of row: dims 32q..32q+31
    const int rid = tt >> 2;   // 0..63
    float4 gpv[8], gcv[8];
    {
        const float4* GP = reinterpret_cast<const float4*>(gbuf[half])     + q * 8;
        const float4* GC = reinterpret_cast<const float4*>(gbuf[half ^ 1]) + q * 8;
#pragma unroll
        for (int i = 0; i < 8; ++i) { gpv[i] = GP[i]; gcv[i] = GC[i]; }
    }

    float acc = 0.f;
    // staged rows: bf16 from LDS
    for (int idx = rid; idx < staged; idx += 64) {
        const unsigned char* rowp = zb + (size_t)idx * ROWB;
        const int x = idx & 7;
        float p = 0.f, cr = 0.f, ssv = 0.f;
#pragma unroll
        for (int j = 0; j < 4; ++j) {
            const int chunk = (q * 4 + j) ^ x;
            const uint4 u = *reinterpret_cast<const uint4*>(rowp + chunk * 16);
            const float4 gp = gpv[2 * j], gq = gpv[2 * j + 1];
            const float4 hp = gcv[2 * j], hq = gcv[2 * j + 1];
            const float f0 = __uint_as_float(u.x << 16);
            const float f1 = __uint_as_float(u.x & 0xffff0000u);
            const float f2 = __uint_as_float(u.y << 16);
            const float f3 = __uint_as_float(u.y & 0xffff0000u);
            const float f4 = __uint_as_float(u.z << 16);
            const float f5 = __uint_as_float(u.z & 0xffff0000u);
            const float f6 = __uint_as_float(u.w << 16);
            const float f7 = __uint_as_float(u.w & 0xffff0000u);
            p   += f0*gp.x + f1*gp.y + f2*gp.z + f3*gp.w
                 + f4*gq.x + f5*gq.y + f6*gq.z + f7*gq.w;
            cr  += f0*hp.x + f1*hp.y + f2*hp.z + f3*hp.w
                 + f4*hq.x + f5*hq.y + f6*hq.z + f7*hq.w;
            ssv += f0*f0 + f1*f1 + f2*f2 + f3*f3 + f4*f4 + f5*f5 + f6*f6 + f7*f7;
        }
        p   += __shfl_xor(p, 1, 64);   p   += __shfl_xor(p, 2, 64);
        cr  += __shfl_xor(cr, 1, 64);  cr  += __shfl_xor(cr, 2, 64);
        ssv += __shfl_xor(ssv, 1, 64); ssv += __shfl_xor(ssv, 2, 64);
        if (q == 0) {
            const float invz  = 1.0f / fmaxf(sqrtf(ssv), 1e-12f);
            const float pos   = p  * invz;
            const float cross = cr * invz;
            const float d = log1pf(__expf(-cross)) - log1pf(__expf(-pos));
            acc += d * d;
        }
    }
    // un-staged rows: exact fp32 from global (L3-resident — just streamed in A)
    for (int idx = staged + rid; idx < cnt; idx += 64) {
        const int row = start + idx;
        const float4* Z = reinterpret_cast<const float4*>(z);
        float p = 0.f, cr = 0.f, ssv = 0.f;
#pragma unroll
        for (int i = 0; i < 8; ++i) {
            float4 zv = Z[(size_t)row * 32 + q * 8 + i];
            p   += zv.x * gpv[i].x + zv.y * gpv[i].y + zv.z * gpv[i].z + zv.w * gpv[i].w;
            cr  += zv.x * gcv[i].x + zv.y * gcv[i].y + zv.z * gcv[i].z + zv.w * gcv[i].w;
            ssv += zv.x * zv.x + zv.y * zv.y + zv.z * zv.z + zv.w * zv.w;
        }
        p   += __shfl_xor(p, 1, 64);   p   += __shfl_xor(p, 2, 64);
        cr  += __shfl_xor(cr, 1, 64);  cr  += __shfl_xor(cr, 2, 64);
        ssv += __shfl_xor(ssv, 1, 64); ssv += __shfl_xor(ssv, 2, 64);
        if (q == 0) {
            const float invz  = 1.0f / fmaxf(sqrtf(ssv), 1e-12f);
            const float pos   = p  * invz;
            const float cross = cr * invz;
            const float d = log1pf(__expf(-cross)) - log1pf(__expf(-pos));
            acc += d * d;
        }
    }

#pragma unroll
    for (int m = 1; m <= 32; m <<= 1) acc += __shfl_xor(acc, m, 64);
    if ((tt & 63) == 0) warr[half][tt >> 6] = acc;
    __syncthreads();
    if (tt == 0)
        dsq[half * NUM_GRAPHS + s] = warr[half][0] + warr[half][1]
                                   + warr[half][2] + warr[half][3];
}

// Single block, 1024 threads: dsq[0..511] -> s0, dsq[512..1023] -> s1.
__global__ __launch_bounds__(1024) void finalize_kernel(const float* __restrict__ dsq,
                                                        float* __restrict__ out) {
    const int t = threadIdx.x;
    float v = dsq[t];
#pragma unroll
    for (int m = 1; m <= 32; m <<= 1) v += __shfl_xor(v, m, 64);
    __shared__ float w[16];
    if ((t & 63) == 0) w[t >> 6] = v;
    __syncthreads();
    if (t == 0) {
        float s0 = 0.f, s1 = 0.f;
#pragma unroll
        for (int i = 0; i < 8; ++i)  s0 += w[i];
#pragma unroll
        for (int i = 8; i < 16; ++i) s1 += w[i];
        out[0] = sqrtf(s0) + sqrtf(s1);
    }
}

extern "C" void kernel_launch(void* const* d_in, const int* in_sizes, int n_in,
                              void* d_out, int out_size, void* d_ws, size_t ws_size,
                              hipStream_t stream) {
    const float* z1 = (const float*)d_in[0];
    const float* z2 = (const float*)d_in[1];
    const int*   b1 = (const int*)d_in[2];
    const int*   b2 = (const int*)d_in[3];
    const int N = in_sizes[2];

    float* dsq = (float*)d_ws;   // 1024 floats, fully written every call

    const int smem_bytes = 2 * CAP * ROWB;   // 69632 B dynamic (+ ~9.3 KB static)
    (void)hipFuncSetAttribute((const void*)fused_gcl,
                              hipFuncAttributeMaxDynamicSharedMemorySize, smem_bytes);

    fused_gcl<<<NUM_GRAPHS, 512, smem_bytes, stream>>>(z1, z2, b1, b2, dsq, N);
    finalize_kernel<<<1, 1024, 0, stream>>>(dsq, (float*)d_out);
}